// Round 1
// baseline (882.507 us; speedup 1.0000x reference)
//
#include <hip/hip_runtime.h>

#define H      128
#define OBSROW 141
#define GPB    16     // graphs per block (MFMA M dimension)

typedef __bf16 bf16x8 __attribute__((ext_vector_type(8)));
typedef float  f32x4  __attribute__((ext_vector_type(4)));

__device__ __forceinline__ unsigned short f2bf(float f) {
    unsigned int u = __builtin_bit_cast(unsigned int, f);
    u += 0x7fffu + ((u >> 16) & 1u);          // round-to-nearest-even
    return (unsigned short)(u >> 16);
}
__device__ __forceinline__ float eluf(float v) {
    return v > 0.0f ? v : (__expf(v) - 1.0f);
}

union BFU { unsigned short s[8]; bf16x8 v; };

__device__ __forceinline__ bf16x8 loadw8(const float* __restrict__ p) {
    const float4 w0 = *(const float4*)p;
    const float4 w1 = *(const float4*)(p + 4);
    BFU u;
    u.s[0]=f2bf(w0.x); u.s[1]=f2bf(w0.y); u.s[2]=f2bf(w0.z); u.s[3]=f2bf(w0.w);
    u.s[4]=f2bf(w1.x); u.s[5]=f2bf(w1.y); u.s[6]=f2bf(w1.z); u.s[7]=f2bf(w1.w);
    return u.v;
}

// X layout: [node 13][hc=h/8 16][graph 16][hi 8]  (bf16) -> A-frag = 16B contiguous
#define XIDX(n,hc,g,hi) (((((n)*16 + (hc))*16 + (g))*8) + (hi))

__launch_bounds__(256, 2)
__global__ void gnn_fused(const float* __restrict__ obs,
                          const float* __restrict__ We_b, const float* __restrict__ be_b,
                          const float* __restrict__ We_j, const float* __restrict__ be_j,
                          const float* __restrict__ W_rel, const float* __restrict__ W_root,
                          const float* __restrict__ b_rel,
                          const float* __restrict__ W_dec, const float* __restrict__ b_dec,
                          float* __restrict__ out, int B)
{
    __shared__ __align__(16) unsigned short Xs[13*16*16*8];   // 53248 B
    __shared__ __align__(16) unsigned short Fs[3072];         // 6144 B feature staging

    const int tid  = threadIdx.x;
    const int wave = tid >> 6;
    const int lane = tid & 63;
    const int q    = lane >> 4;    // quad 0..3
    const int c    = lane & 15;    // col-in-tile / graph-in-chunk
    const int g0   = blockIdx.x * GPB;

    // in-edge adjacency of the fixed 24-edge tree (both directions folded in)
    static constexpr int INDEG[13]    = {4,2,2,1,2,2,1,2,2,1,2,2,1};
    static constexpr int INSRC[13][4] = {
        {1,4,7,10},{0,2,0,0},{1,3,0,0},{2,0,0,0},{0,5,0,0},{4,6,0,0},{5,0,0,0},
        {0,8,0,0},{7,9,0,0},{8,0,0,0},{0,11,0,0},{10,12,0,0},{11,0,0,0}};

    // ---------------- encoder: node 0 (base features, K 33 -> 64) ----------------
    for (int s = tid; s < 1024; s += 256) {
        const int fc = s >> 7, rem = s & 127, g = rem >> 3, hi = rem & 7;
        const int f = fc*8 + hi;
        float v = 0.0f;
        if (f < 33 && (g0 + g) < B) {
            const int tt = f / 11, i = f % 11;   // BASE_IDX[i] = i<9 ? i : 36+i
            v = obs[(g0+g)*OBSROW + tt*47 + (i < 9 ? i : 36 + i)];
        }
        Fs[s] = f2bf(v);
    }
    __syncthreads();
    #pragma unroll
    for (int t = 0; t < 2; t++) {
        const int jt = wave + t*4;     // o-tile 0..7
        const int o  = jt*16 + c;
        BFU u0, u1;
        #pragma unroll
        for (int j = 0; j < 8; j++) {
            const int f1 = 32 + q*8 + j;
            u0.s[j] = f2bf(We_b[o*33 + q*8 + j]);                  // f0 = 0..31 < 33
            u1.s[j] = f2bf(f1 < 33 ? We_b[o*33 + f1] : 0.0f);
        }
        f32x4 acc = {0.f,0.f,0.f,0.f};
        const bf16x8 a0 = *(const bf16x8*)&Fs[((0*4 + q)*16 + c)*8];
        const bf16x8 a1 = *(const bf16x8*)&Fs[((1*4 + q)*16 + c)*8];
        acc = __builtin_amdgcn_mfma_f32_16x16x32_bf16(a0, u0.v, acc, 0,0,0);
        acc = __builtin_amdgcn_mfma_f32_16x16x32_bf16(a1, u1.v, acc, 0,0,0);
        const float bias = be_b[o];
        #pragma unroll
        for (int r = 0; r < 4; r++) {
            const float v = eluf(acc[r] + bias);
            Xs[XIDX(0, jt*2 + (c>>3), q*4 + r, c & 7)] = f2bf(v);  // row=graph, col=o
        }
    }
    __syncthreads();

    // ---------------- encoder: joints (nodes 1..12, K 9 -> 32) ----------------
    #pragma unroll 1
    for (int rnd = 0; rnd < 2; rnd++) {
        const int nbase = 1 + rnd*6;
        for (int s = tid; s < 3072; s += 256) {
            const int nd = s >> 9, rem = s & 511;
            const int fc = rem >> 7, g = (rem >> 3) & 15, hi = rem & 7;
            const int f = fc*8 + hi;
            float v = 0.0f;
            if (f < 9 && (g0 + g) < B) {
                const int jj = nbase + nd - 1;    // joint index 0..11
                v = obs[(g0+g)*OBSROW + (f/3)*47 + 9 + (f%3)*12 + jj];
            }
            Fs[s] = f2bf(v);   // layout ((nd*4+fc)*16+g)*8+hi == s
        }
        __syncthreads();
        #pragma unroll
        for (int t = 0; t < 2; t++) {
            const int jt = wave + t*4;
            const int o  = jt*16 + c;
            BFU uj;
            #pragma unroll
            for (int j = 0; j < 8; j++) {
                const int f = q*8 + j;
                uj.s[j] = f2bf(f < 9 ? We_j[o*9 + f] : 0.0f);
            }
            const float bias = be_j[o];
            #pragma unroll
            for (int nd = 0; nd < 6; nd++) {
                f32x4 acc = {0.f,0.f,0.f,0.f};
                const bf16x8 a = *(const bf16x8*)&Fs[((nd*4 + q)*16 + c)*8];
                acc = __builtin_amdgcn_mfma_f32_16x16x32_bf16(a, uj.v, acc, 0,0,0);
                #pragma unroll
                for (int r = 0; r < 4; r++) {
                    const float v = eluf(acc[r] + bias);
                    Xs[XIDX(nbase + nd, jt*2 + (c>>3), q*4 + r, c & 7)] = f2bf(v);
                }
            }
        }
        __syncthreads();
    }

    // ---------------- 3 GraphConv layers ----------------
    #pragma unroll 1
    for (int l = 0; l < 3; l++) {
        const float* __restrict__ Wr = W_rel  + l*H*H;
        const float* __restrict__ Wo = W_root + l*H*H;
        unsigned int stash[2][13][2];
        #pragma unroll
        for (int t = 0; t < 2; t++) {
            const int jt = wave + t*4;
            const int o  = jt*16 + c;
            bf16x8 brel[4], broot[4];
            #pragma unroll
            for (int k = 0; k < 4; k++) {
                brel[k]  = loadw8(Wr + o*H + k*32 + q*8);   // B[k][n]=W[o][h]
                broot[k] = loadw8(Wo + o*H + k*32 + q*8);
            }
            f32x4 crel[13], croot[13];
            #pragma unroll
            for (int n = 0; n < 13; n++) {
                f32x4 ar = {0.f,0.f,0.f,0.f}, ao = {0.f,0.f,0.f,0.f};
                #pragma unroll
                for (int k = 0; k < 4; k++) {
                    const bf16x8 a = *(const bf16x8*)&Xs[XIDX(n, k*4 + q, c, 0)];
                    ar = __builtin_amdgcn_mfma_f32_16x16x32_bf16(a, brel[k],  ar, 0,0,0);
                    ao = __builtin_amdgcn_mfma_f32_16x16x32_bf16(a, broot[k], ao, 0,0,0);
                }
                crel[n] = ar; croot[n] = ao;
            }
            const float bias = b_rel[l*H + o];
            #pragma unroll
            for (int n = 0; n < 13; n++) {
                f32x4 acc = croot[n];
                #pragma unroll
                for (int e = 0; e < 4; e++)
                    if (e < INDEG[n]) acc += crel[INSRC[n][e]];   // scatter-add as tile adds
                const float v0 = eluf(acc[0] + bias);
                const float v1 = eluf(acc[1] + bias);
                const float v2 = eluf(acc[2] + bias);
                const float v3 = eluf(acc[3] + bias);
                stash[t][n][0] = (unsigned)f2bf(v0) | ((unsigned)f2bf(v1) << 16);
                stash[t][n][1] = (unsigned)f2bf(v2) | ((unsigned)f2bf(v3) << 16);
            }
        }
        __syncthreads();   // all waves done READING old X
        #pragma unroll
        for (int t = 0; t < 2; t++) {
            const int jt = wave + t*4;
            const int hc = jt*2 + (c >> 3);
            const int hi = c & 7;
            #pragma unroll
            for (int n = 0; n < 13; n++) {
                Xs[XIDX(n, hc, q*4+0, hi)] = (unsigned short)(stash[t][n][0]);
                Xs[XIDX(n, hc, q*4+1, hi)] = (unsigned short)(stash[t][n][0] >> 16);
                Xs[XIDX(n, hc, q*4+2, hi)] = (unsigned short)(stash[t][n][1]);
                Xs[XIDX(n, hc, q*4+3, hi)] = (unsigned short)(stash[t][n][1] >> 16);
            }
        }
        __syncthreads();   // new X visible
    }

    // ---------------- decoder: out[g][j] = x[j+1]·W_dec + b_dec ----------------
    {
        float wd[32];
        #pragma unroll
        for (int i4 = 0; i4 < 8; i4++) {
            const float4 wv = *(const float4*)&W_dec[q*32 + i4*4];
            wd[i4*4+0] = wv.x; wd[i4*4+1] = wv.y; wd[i4*4+2] = wv.z; wd[i4*4+3] = wv.w;
        }
        const float bd = b_dec[0];
        #pragma unroll
        for (int jj = 0; jj < 3; jj++) {
            const int j = wave*3 + jj;          // 0..11
            float s = 0.0f;
            #pragma unroll
            for (int hq = 0; hq < 4; hq++) {    // lane covers h = q*32 + hq*8 + hi
                const bf16x8 xv = *(const bf16x8*)&Xs[XIDX(j+1, q*4 + hq, c, 0)];
                #pragma unroll
                for (int hi = 0; hi < 8; hi++)
                    s += (float)xv[hi] * wd[hq*8 + hi];
            }
            s += __shfl_xor(s, 16);
            s += __shfl_xor(s, 32);
            if (q == 0 && (g0 + c) < B)
                out[(g0 + c)*12 + j] = s + bd;
        }
    }
}

extern "C" void kernel_launch(void* const* d_in, const int* in_sizes, int n_in,
                              void* d_out, int out_size, void* d_ws, size_t ws_size,
                              hipStream_t stream) {
    const float* obs   = (const float*)d_in[0];
    const float* We_b  = (const float*)d_in[1];
    const float* be_b  = (const float*)d_in[2];
    const float* We_j  = (const float*)d_in[3];
    const float* be_j  = (const float*)d_in[4];
    const float* W_rel = (const float*)d_in[5];
    const float* W_root= (const float*)d_in[6];
    const float* b_rel = (const float*)d_in[7];
    const float* W_dec = (const float*)d_in[8];
    const float* b_dec = (const float*)d_in[9];
    // d_in[10]/d_in[11] (src/dst) are the fixed tree edges; adjacency is baked in.
    float* out = (float*)d_out;

    const int B = in_sizes[0] / OBSROW;
    const int blocks = (B + GPB - 1) / GPB;
    gnn_fused<<<blocks, 256, 0, stream>>>(obs, We_b, be_b, We_j, be_j,
                                          W_rel, W_root, b_rel, W_dec, b_dec,
                                          out, B);
}

// Round 3
// 798.110 us; speedup vs baseline: 1.1057x; 1.1057x over previous
//
#include <hip/hip_runtime.h>

#define H      128
#define OBSROW 141
#define GPB    16     // graphs per block (MFMA M dimension)

typedef __bf16 bf16x8 __attribute__((ext_vector_type(8)));
typedef float  f32x4  __attribute__((ext_vector_type(4)));

__device__ __forceinline__ unsigned short f2bf(float f) {
    unsigned int u = __builtin_bit_cast(unsigned int, f);
    u += 0x7fffu + ((u >> 16) & 1u);          // round-to-nearest-even
    return (unsigned short)(u >> 16);
}
__device__ __forceinline__ float eluf(float v) {
    return v > 0.0f ? v : (__expf(v) - 1.0f);
}

union BFU { unsigned short s[8]; bf16x8 v; };

__device__ __forceinline__ bf16x8 loadw8(const float* __restrict__ p) {
    const float4 w0 = *(const float4*)p;
    const float4 w1 = *(const float4*)(p + 4);
    BFU u;
    u.s[0]=f2bf(w0.x); u.s[1]=f2bf(w0.y); u.s[2]=f2bf(w0.z); u.s[3]=f2bf(w0.w);
    u.s[4]=f2bf(w1.x); u.s[5]=f2bf(w1.y); u.s[6]=f2bf(w1.z); u.s[7]=f2bf(w1.w);
    return u.v;
}

// X layout: [node 13][hc=h/8 16][graph 16][hi 8]  (bf16) -> A-frag = 16B contiguous
#define XIDX(n,hc,g,hi) (((((n)*16 + (hc))*16 + (g))*8) + (hi))

__launch_bounds__(256, 2)
__global__ void gnn_fused(const float* __restrict__ obs,
                          const float* __restrict__ We_b, const float* __restrict__ be_b,
                          const float* __restrict__ We_j, const float* __restrict__ be_j,
                          const float* __restrict__ W_rel, const float* __restrict__ W_root,
                          const float* __restrict__ b_rel,
                          const float* __restrict__ W_dec, const float* __restrict__ b_dec,
                          float* __restrict__ out, int B)
{
    __shared__ __align__(16) unsigned short Xs[13*16*16*8];   // 53248 B
    __shared__ __align__(16) unsigned short Fs[3072];         // 6144 B feature staging

    const int tid  = threadIdx.x;
    const int wave = tid >> 6;
    const int lane = tid & 63;
    const int q    = lane >> 4;    // quad 0..3
    const int c    = lane & 15;    // col-in-tile / graph-in-chunk
    const int g0   = blockIdx.x * GPB;

    // per-thread LDS base for A-frag reads: frag(n,k) at xrd + n*2048 + k*512 shorts
    // (frag hc = k*4 + q  ->  h = k*32 + q*8 + hi, matching MFMA A layout k=q*8+j)
    const unsigned short* xrd = Xs + q*128 + c*8;

    // in-edge adjacency of the fixed 24-edge tree (both directions folded in)
    static constexpr int INDEG[13]    = {4,2,2,1,2,2,1,2,2,1,2,2,1};
    static constexpr int INSRC[13][4] = {
        {1,4,7,10},{0,2,0,0},{1,3,0,0},{2,0,0,0},{0,5,0,0},{4,6,0,0},{5,0,0,0},
        {0,8,0,0},{7,9,0,0},{8,0,0,0},{0,11,0,0},{10,12,0,0},{11,0,0,0}};

    // ---------------- encoder: node 0 (base features, K 33 -> 64) ----------------
    for (int s = tid; s < 1024; s += 256) {
        const int fc = s >> 7, rem = s & 127, g = rem >> 3, hi = rem & 7;
        const int f = fc*8 + hi;
        float v = 0.0f;
        if (f < 33 && (g0 + g) < B) {
            const int tt = f / 11, i = f % 11;   // BASE_IDX[i] = i<9 ? i : 36+i
            v = obs[(g0+g)*OBSROW + tt*47 + (i < 9 ? i : 36 + i)];
        }
        Fs[s] = f2bf(v);
    }
    __syncthreads();
    #pragma unroll
    for (int t = 0; t < 2; t++) {
        const int jt = wave + t*4;     // o-tile 0..7
        const int o  = jt*16 + c;
        BFU u0, u1;
        #pragma unroll
        for (int j = 0; j < 8; j++) {
            const int f1 = 32 + q*8 + j;
            u0.s[j] = f2bf(We_b[o*33 + q*8 + j]);                  // f0 = 0..31 < 33
            u1.s[j] = f2bf(f1 < 33 ? We_b[o*33 + f1] : 0.0f);
        }
        f32x4 acc = {0.f,0.f,0.f,0.f};
        const bf16x8 a0 = *(const bf16x8*)&Fs[((0*4 + q)*16 + c)*8];
        const bf16x8 a1 = *(const bf16x8*)&Fs[((1*4 + q)*16 + c)*8];
        acc = __builtin_amdgcn_mfma_f32_16x16x32_bf16(a0, u0.v, acc, 0,0,0);
        acc = __builtin_amdgcn_mfma_f32_16x16x32_bf16(a1, u1.v, acc, 0,0,0);
        const float bias = be_b[o];
        #pragma unroll
        for (int r = 0; r < 4; r++) {
            const float v = eluf(acc[r] + bias);
            Xs[XIDX(0, jt*2 + (c>>3), q*4 + r, c & 7)] = f2bf(v);  // row=graph, col=o
        }
    }
    __syncthreads();

    // ---------------- encoder: joints (nodes 1..12, K 9 -> 32) ----------------
    #pragma unroll 1
    for (int rnd = 0; rnd < 2; rnd++) {
        const int nbase = 1 + rnd*6;
        for (int s = tid; s < 3072; s += 256) {
            const int nd = s >> 9, rem = s & 511;
            const int fc = rem >> 7, g = (rem >> 3) & 15, hi = rem & 7;
            const int f = fc*8 + hi;
            float v = 0.0f;
            if (f < 9 && (g0 + g) < B) {
                const int jj = nbase + nd - 1;    // joint index 0..11
                v = obs[(g0+g)*OBSROW + (f/3)*47 + 9 + (f%3)*12 + jj];
            }
            Fs[s] = f2bf(v);   // layout ((nd*4+fc)*16+g)*8+hi == s
        }
        __syncthreads();
        #pragma unroll
        for (int t = 0; t < 2; t++) {
            const int jt = wave + t*4;
            const int o  = jt*16 + c;
            BFU uj;
            #pragma unroll
            for (int j = 0; j < 8; j++) {
                const int f = q*8 + j;
                uj.s[j] = f2bf(f < 9 ? We_j[o*9 + f] : 0.0f);
            }
            const float bias = be_j[o];
            #pragma unroll
            for (int nd = 0; nd < 6; nd++) {
                f32x4 acc = {0.f,0.f,0.f,0.f};
                const bf16x8 a = *(const bf16x8*)&Fs[((nd*4 + q)*16 + c)*8];
                acc = __builtin_amdgcn_mfma_f32_16x16x32_bf16(a, uj.v, acc, 0,0,0);
                #pragma unroll
                for (int r = 0; r < 4; r++) {
                    const float v = eluf(acc[r] + bias);
                    Xs[XIDX(nbase + nd, jt*2 + (c>>3), q*4 + r, c & 7)] = f2bf(v);
                }
            }
        }
        __syncthreads();
    }

    // ---------------- 3 GraphConv layers (two-phase: rel then root) ----------------
    #pragma unroll 1
    for (int l = 0; l < 3; l++) {
        const float* __restrict__ Wr = W_rel  + l*H*H;
        const float* __restrict__ Wo = W_root + l*H*H;
        unsigned int stash[2][13][2];
        #pragma unroll
        for (int t = 0; t < 2; t++) {
            const int jt = wave + t*4;
            const int o  = jt*16 + c;
            f32x4 crel[13];
            // ---- phase 1: crel[n] = W_rel · x[n]  (52 regs of acc, 16 of B-frags)
            {
                bf16x8 bw[4];
                #pragma unroll
                for (int k = 0; k < 4; k++)
                    bw[k] = loadw8(Wr + o*H + k*32 + q*8);
                #pragma unroll
                for (int n = 0; n < 13; n++) {
                    f32x4 a = {0.f,0.f,0.f,0.f};
                    #pragma unroll
                    for (int k = 0; k < 4; k++) {
                        const bf16x8 xa = *(const bf16x8*)(xrd + n*2048 + k*512);
                        a = __builtin_amdgcn_mfma_f32_16x16x32_bf16(xa, bw[k], a, 0,0,0);
                    }
                    crel[n] = a;
                }
            }
            // ---- phase 2: acc = sum_in crel[src]; acc += W_root · x[n]; elu -> stash
            {
                bf16x8 bw[4];
                #pragma unroll
                for (int k = 0; k < 4; k++)
                    bw[k] = loadw8(Wo + o*H + k*32 + q*8);
                const float bias = b_rel[l*H + o];
                #pragma unroll
                for (int n = 0; n < 13; n++) {
                    f32x4 acc = crel[INSRC[n][0]];
                    #pragma unroll
                    for (int e = 1; e < 4; e++)
                        if (e < INDEG[n]) acc += crel[INSRC[n][e]];
                    #pragma unroll
                    for (int k = 0; k < 4; k++) {
                        const bf16x8 xa = *(const bf16x8*)(xrd + n*2048 + k*512);
                        acc = __builtin_amdgcn_mfma_f32_16x16x32_bf16(xa, bw[k], acc, 0,0,0);
                    }
                    const float v0 = eluf(acc[0] + bias);
                    const float v1 = eluf(acc[1] + bias);
                    const float v2 = eluf(acc[2] + bias);
                    const float v3 = eluf(acc[3] + bias);
                    stash[t][n][0] = (unsigned)f2bf(v0) | ((unsigned)f2bf(v1) << 16);
                    stash[t][n][1] = (unsigned)f2bf(v2) | ((unsigned)f2bf(v3) << 16);
                }
            }
        }
        __syncthreads();   // all waves done READING old X
        #pragma unroll
        for (int t = 0; t < 2; t++) {
            const int jt = wave + t*4;
            const int hc = jt*2 + (c >> 3);
            const int hi = c & 7;
            #pragma unroll
            for (int n = 0; n < 13; n++) {
                Xs[XIDX(n, hc, q*4+0, hi)] = (unsigned short)(stash[t][n][0]);
                Xs[XIDX(n, hc, q*4+1, hi)] = (unsigned short)(stash[t][n][0] >> 16);
                Xs[XIDX(n, hc, q*4+2, hi)] = (unsigned short)(stash[t][n][1]);
                Xs[XIDX(n, hc, q*4+3, hi)] = (unsigned short)(stash[t][n][1] >> 16);
            }
        }
        __syncthreads();   // new X visible
    }

    // ---------------- decoder: out[g][j] = x[j+1]·W_dec + b_dec ----------------
    {
        // decoder base: hc = q*4 + hq  ->  h = q*32 + hq*8 + hi (matches wd indexing)
        const unsigned short* xdec = Xs + q*512 + c*8;
        float wd[32];
        #pragma unroll
        for (int i4 = 0; i4 < 8; i4++) {
            const float4 wv = *(const float4*)&W_dec[q*32 + i4*4];
            wd[i4*4+0] = wv.x; wd[i4*4+1] = wv.y; wd[i4*4+2] = wv.z; wd[i4*4+3] = wv.w;
        }
        const float bd = b_dec[0];
        #pragma unroll
        for (int jj = 0; jj < 3; jj++) {
            const int j = wave*3 + jj;          // 0..11
            float s = 0.0f;
            #pragma unroll
            for (int hq = 0; hq < 4; hq++) {    // lane covers h = q*32 + hq*8 + hi
                const bf16x8 xv = *(const bf16x8*)(xdec + (j+1)*2048 + hq*128);
                #pragma unroll
                for (int hi = 0; hi < 8; hi++)
                    s += (float)xv[hi] * wd[hq*8 + hi];
            }
            s += __shfl_xor(s, 16);
            s += __shfl_xor(s, 32);
            if (q == 0 && (g0 + c) < B)
                out[(g0 + c)*12 + j] = s + bd;
        }
    }
}

extern "C" void kernel_launch(void* const* d_in, const int* in_sizes, int n_in,
                              void* d_out, int out_size, void* d_ws, size_t ws_size,
                              hipStream_t stream) {
    const float* obs   = (const float*)d_in[0];
    const float* We_b  = (const float*)d_in[1];
    const float* be_b  = (const float*)d_in[2];
    const float* We_j  = (const float*)d_in[3];
    const float* be_j  = (const float*)d_in[4];
    const float* W_rel = (const float*)d_in[5];
    const float* W_root= (const float*)d_in[6];
    const float* b_rel = (const float*)d_in[7];
    const float* W_dec = (const float*)d_in[8];
    const float* b_dec = (const float*)d_in[9];
    // d_in[10]/d_in[11] (src/dst) are the fixed tree edges; adjacency is baked in.
    float* out = (float*)d_out;

    const int B = in_sizes[0] / OBSROW;
    const int blocks = (B + GPB - 1) / GPB;
    gnn_fused<<<blocks, 256, 0, stream>>>(obs, We_b, be_b, We_j, be_j,
                                          W_rel, W_root, b_rel, W_dec, b_dec,
                                          out, B);
}

// Round 4
// 310.154 us; speedup vs baseline: 2.8454x; 2.5733x over previous
//
#include <hip/hip_runtime.h>

#define H      128
#define OBSROW 141
#define GPB    16     // graphs per block (MFMA M dimension)
#define NT     512    // 8 waves; each wave owns ONE 16-col o-tile

typedef __bf16 bf16x8 __attribute__((ext_vector_type(8)));
typedef float  f32x4  __attribute__((ext_vector_type(4)));

__device__ __forceinline__ unsigned short f2bf(float f) {
    unsigned int u = __builtin_bit_cast(unsigned int, f);
    u += 0x7fffu + ((u >> 16) & 1u);          // round-to-nearest-even
    return (unsigned short)(u >> 16);
}
__device__ __forceinline__ float eluf(float v) {
    return v > 0.0f ? v : (__expf(v) - 1.0f);
}

union BFU { unsigned short s[8]; bf16x8 v; };

__device__ __forceinline__ bf16x8 loadw8(const float* __restrict__ p) {
    const float4 w0 = *(const float4*)p;
    const float4 w1 = *(const float4*)(p + 4);
    BFU u;
    u.s[0]=f2bf(w0.x); u.s[1]=f2bf(w0.y); u.s[2]=f2bf(w0.z); u.s[3]=f2bf(w0.w);
    u.s[4]=f2bf(w1.x); u.s[5]=f2bf(w1.y); u.s[6]=f2bf(w1.z); u.s[7]=f2bf(w1.w);
    return u.v;
}

// X layout: [node 13][hc=h/8 16][graph 16][hi 8]  (bf16) -> A-frag = 16B contiguous
#define XIDX(n,hc,g,hi) (((((n)*16 + (hc))*16 + (g))*8) + (hi))

__launch_bounds__(NT, 2)   // 2 waves/EU min -> 256 unified VGPR+AGPR cap; demand ~210
__global__ void gnn_fused(const float* __restrict__ obs,
                          const float* __restrict__ We_b, const float* __restrict__ be_b,
                          const float* __restrict__ We_j, const float* __restrict__ be_j,
                          const float* __restrict__ W_rel, const float* __restrict__ W_root,
                          const float* __restrict__ b_rel,
                          const float* __restrict__ W_dec, const float* __restrict__ b_dec,
                          float* __restrict__ out, int B)
{
    __shared__ __align__(16) unsigned short Xs[13*16*16*8];   // 53248 B
    __shared__ __align__(16) unsigned short Fs[3072];         // 6144 B feature staging

    const int tid  = threadIdx.x;
    const int wave = tid >> 6;     // 0..7 == this wave's o-tile
    const int lane = tid & 63;
    const int q    = lane >> 4;    // quad 0..3
    const int c    = lane & 15;    // col-in-tile / graph-in-chunk
    const int g0   = blockIdx.x * GPB;

    // per-thread LDS base for A-frag reads: frag(n,k) at xrd + n*2048 + k*512 shorts
    // (frag hc = k*4 + q  ->  h = k*32 + q*8 + hi, matching MFMA A layout k=q*8+j)
    const unsigned short* xrd = Xs + q*128 + c*8;

    // in-edge adjacency of the fixed 24-edge tree (both directions folded in)
    static constexpr int INDEG[13]    = {4,2,2,1,2,2,1,2,2,1,2,2,1};
    static constexpr int INSRC[13][4] = {
        {1,4,7,10},{0,2,0,0},{1,3,0,0},{2,0,0,0},{0,5,0,0},{4,6,0,0},{5,0,0,0},
        {0,8,0,0},{7,9,0,0},{8,0,0,0},{0,11,0,0},{10,12,0,0},{11,0,0,0}};

    // ---------------- encoder: node 0 (base features, K 33 -> 64) ----------------
    for (int s = tid; s < 1024; s += NT) {
        const int fc = s >> 7, rem = s & 127, g = rem >> 3, hi = rem & 7;
        const int f = fc*8 + hi;
        float v = 0.0f;
        if (f < 33 && (g0 + g) < B) {
            const int tt = f / 11, i = f % 11;   // BASE_IDX[i] = i<9 ? i : 36+i
            v = obs[(g0+g)*OBSROW + tt*47 + (i < 9 ? i : 36 + i)];
        }
        Fs[s] = f2bf(v);
    }
    __syncthreads();
    {
        const int jt = wave;           // o-tile 0..7
        const int o  = jt*16 + c;
        BFU u0, u1;
        #pragma unroll
        for (int j = 0; j < 8; j++) {
            const int f1 = 32 + q*8 + j;
            u0.s[j] = f2bf(We_b[o*33 + q*8 + j]);                  // f0 = 0..31 < 33
            u1.s[j] = f2bf(f1 < 33 ? We_b[o*33 + f1] : 0.0f);
        }
        f32x4 acc = {0.f,0.f,0.f,0.f};
        const bf16x8 a0 = *(const bf16x8*)&Fs[((0*4 + q)*16 + c)*8];
        const bf16x8 a1 = *(const bf16x8*)&Fs[((1*4 + q)*16 + c)*8];
        acc = __builtin_amdgcn_mfma_f32_16x16x32_bf16(a0, u0.v, acc, 0,0,0);
        acc = __builtin_amdgcn_mfma_f32_16x16x32_bf16(a1, u1.v, acc, 0,0,0);
        const float bias = be_b[o];
        #pragma unroll
        for (int r = 0; r < 4; r++) {
            const float v = eluf(acc[r] + bias);
            Xs[XIDX(0, jt*2 + (c>>3), q*4 + r, c & 7)] = f2bf(v);  // row=graph, col=o
        }
    }
    __syncthreads();

    // ---------------- encoder: joints (nodes 1..12, K 9 -> 32) ----------------
    #pragma unroll 1
    for (int rnd = 0; rnd < 2; rnd++) {
        const int nbase = 1 + rnd*6;
        for (int s = tid; s < 3072; s += NT) {
            const int nd = s >> 9, rem = s & 511;
            const int fc = rem >> 7, g = (rem >> 3) & 15, hi = rem & 7;
            const int f = fc*8 + hi;
            float v = 0.0f;
            if (f < 9 && (g0 + g) < B) {
                const int jj = nbase + nd - 1;    // joint index 0..11
                v = obs[(g0+g)*OBSROW + (f/3)*47 + 9 + (f%3)*12 + jj];
            }
            Fs[s] = f2bf(v);   // layout ((nd*4+fc)*16+g)*8+hi == s
        }
        __syncthreads();
        {
            const int jt = wave;
            const int o  = jt*16 + c;
            BFU uj;
            #pragma unroll
            for (int j = 0; j < 8; j++) {
                const int f = q*8 + j;
                uj.s[j] = f2bf(f < 9 ? We_j[o*9 + f] : 0.0f);
            }
            const float bias = be_j[o];
            #pragma unroll
            for (int nd = 0; nd < 6; nd++) {
                f32x4 acc = {0.f,0.f,0.f,0.f};
                const bf16x8 a = *(const bf16x8*)&Fs[((nd*4 + q)*16 + c)*8];
                acc = __builtin_amdgcn_mfma_f32_16x16x32_bf16(a, uj.v, acc, 0,0,0);
                #pragma unroll
                for (int r = 0; r < 4; r++) {
                    const float v = eluf(acc[r] + bias);
                    Xs[XIDX(nbase + nd, jt*2 + (c>>3), q*4 + r, c & 7)] = f2bf(v);
                }
            }
        }
        __syncthreads();
    }

    // ---------------- 3 GraphConv layers (single pass, 1 o-tile/wave) ----------------
    #pragma unroll 1
    for (int l = 0; l < 3; l++) {
        const float* __restrict__ Wr = W_rel  + l*H*H;
        const float* __restrict__ Wo = W_root + l*H*H;
        unsigned int stash[13][2];
        {
            const int o = wave*16 + c;
            bf16x8 brel[4], broot[4];
            #pragma unroll
            for (int k = 0; k < 4; k++) {
                brel[k]  = loadw8(Wr + o*H + k*32 + q*8);   // B[k][n]=W[o][h]
                broot[k] = loadw8(Wo + o*H + k*32 + q*8);
            }
            f32x4 crel[13], croot[13];
            #pragma unroll
            for (int n = 0; n < 13; n++) {
                f32x4 ar = {0.f,0.f,0.f,0.f}, ao = {0.f,0.f,0.f,0.f};
                #pragma unroll
                for (int k = 0; k < 4; k++) {
                    const bf16x8 xa = *(const bf16x8*)(xrd + n*2048 + k*512);
                    ar = __builtin_amdgcn_mfma_f32_16x16x32_bf16(xa, brel[k],  ar, 0,0,0);
                    ao = __builtin_amdgcn_mfma_f32_16x16x32_bf16(xa, broot[k], ao, 0,0,0);
                }
                crel[n] = ar; croot[n] = ao;
            }
            const float bias = b_rel[l*H + o];
            #pragma unroll
            for (int n = 0; n < 13; n++) {
                f32x4 acc = croot[n];
                #pragma unroll
                for (int e = 0; e < 4; e++)
                    if (e < INDEG[n]) acc += crel[INSRC[n][e]];   // scatter-add as tile adds
                const float v0 = eluf(acc[0] + bias);
                const float v1 = eluf(acc[1] + bias);
                const float v2 = eluf(acc[2] + bias);
                const float v3 = eluf(acc[3] + bias);
                stash[n][0] = (unsigned)f2bf(v0) | ((unsigned)f2bf(v1) << 16);
                stash[n][1] = (unsigned)f2bf(v2) | ((unsigned)f2bf(v3) << 16);
            }
        }
        __syncthreads();   // all waves done READING old X
        {
            const int hc = wave*2 + (c >> 3);
            const int hi = c & 7;
            #pragma unroll
            for (int n = 0; n < 13; n++) {
                Xs[XIDX(n, hc, q*4+0, hi)] = (unsigned short)(stash[n][0]);
                Xs[XIDX(n, hc, q*4+1, hi)] = (unsigned short)(stash[n][0] >> 16);
                Xs[XIDX(n, hc, q*4+2, hi)] = (unsigned short)(stash[n][1]);
                Xs[XIDX(n, hc, q*4+3, hi)] = (unsigned short)(stash[n][1] >> 16);
            }
        }
        __syncthreads();   // new X visible
    }

    // ---------------- decoder: out[g][j] = x[j+1]·W_dec + b_dec ----------------
    {
        // decoder base: hc = q*4 + hq  ->  h = q*32 + hq*8 + hi (matches wd indexing)
        const unsigned short* xdec = Xs + q*512 + c*8;
        float wd[32];
        #pragma unroll
        for (int i4 = 0; i4 < 8; i4++) {
            const float4 wv = *(const float4*)&W_dec[q*32 + i4*4];
            wd[i4*4+0] = wv.x; wd[i4*4+1] = wv.y; wd[i4*4+2] = wv.z; wd[i4*4+3] = wv.w;
        }
        const float bd = b_dec[0];
        for (int j = wave; j < 12; j += 8) {    // waves 0..3 do two joints, 4..7 one
            float s = 0.0f;
            #pragma unroll
            for (int hq = 0; hq < 4; hq++) {    // lane covers h = q*32 + hq*8 + hi
                const bf16x8 xv = *(const bf16x8*)(xdec + (j+1)*2048 + hq*128);
                #pragma unroll
                for (int hi = 0; hi < 8; hi++)
                    s += (float)xv[hi] * wd[hq*8 + hi];
            }
            s += __shfl_xor(s, 16);
            s += __shfl_xor(s, 32);
            if (q == 0 && (g0 + c) < B)
                out[(g0 + c)*12 + j] = s + bd;
        }
    }
}

extern "C" void kernel_launch(void* const* d_in, const int* in_sizes, int n_in,
                              void* d_out, int out_size, void* d_ws, size_t ws_size,
                              hipStream_t stream) {
    const float* obs   = (const float*)d_in[0];
    const float* We_b  = (const float*)d_in[1];
    const float* be_b  = (const float*)d_in[2];
    const float* We_j  = (const float*)d_in[3];
    const float* be_j  = (const float*)d_in[4];
    const float* W_rel = (const float*)d_in[5];
    const float* W_root= (const float*)d_in[6];
    const float* b_rel = (const float*)d_in[7];
    const float* W_dec = (const float*)d_in[8];
    const float* b_dec = (const float*)d_in[9];
    // d_in[10]/d_in[11] (src/dst) are the fixed tree edges; adjacency is baked in.
    float* out = (float*)d_out;

    const int B = in_sizes[0] / OBSROW;
    const int blocks = (B + GPB - 1) / GPB;
    gnn_fused<<<blocks, NT, 0, stream>>>(obs, We_b, be_b, We_j, be_j,
                                         W_rel, W_root, b_rel, W_dec, b_dec,
                                         out, B);
}